// Round 1
// baseline (140.048 us; speedup 1.0000x reference)
//
#include <hip/hip_runtime.h>

#define IMG 256
#define CROPW 230
#define REMAIN 115

__device__ __forceinline__ int cut_start(int v) {
    int xy = IMG - v;
    return (v <= REMAIN) ? 0 : ((xy <= REMAIN) ? (IMG - CROPW) : (v - REMAIN));
}

// One block per batch: fw -> cam -> argmax -> crop origin
__global__ __launch_bounds__(256) void cam_argmax_kernel(
    const float* __restrict__ fm, int* __restrict__ se_out)
{
    const int b = blockIdx.x;
    const int tid = threadIdx.x;
    const int lane = tid & 63;
    const int wave = tid >> 6;

    __shared__ float fw[512];
    __shared__ float s_val[256];
    __shared__ int   s_idx[256];

    const float* fmb = fm + (size_t)b * 512 * 256;

    // Phase A: fw[c] = mean over 256 spatial elems. 4 waves x 128 channels.
    for (int c = wave * 128; c < wave * 128 + 128; ++c) {
        const float* row = fmb + c * 256;
        float s = row[lane] + row[lane + 64] + row[lane + 128] + row[lane + 192];
        #pragma unroll
        for (int off = 32; off >= 1; off >>= 1)
            s += __shfl_xor(s, off, 64);
        if (lane == 0) fw[c] = s * (1.0f / 256.0f);
    }
    __syncthreads();

    // Phase B: cam[p] for p = tid (relu(fw[c]*fm) summed over channels).
    float acc = 0.0f;
    for (int c = 0; c < 512; ++c) {
        float v = fw[c] * fmb[c * 256 + tid];
        acc += (v > 0.0f) ? v : 0.0f;
    }
    s_val[tid] = acc;   // positive scale (1/512) does not change argmax
    s_idx[tid] = tid;
    __syncthreads();

    // Phase C: argmax with first-occurrence tie-break (max value, min index).
    for (int stride = 128; stride >= 1; stride >>= 1) {
        if (tid < stride) {
            float v2 = s_val[tid + stride]; int i2 = s_idx[tid + stride];
            float v1 = s_val[tid];          int i1 = s_idx[tid];
            if (v2 > v1 || (v2 == v1 && i2 < i1)) { s_val[tid] = v2; s_idx[tid] = i2; }
        }
        __syncthreads();
    }

    if (tid == 0) {
        int idx = s_idx[0];
        int fx = idx >> 4, fy = idx & 15;      // H = W = 16
        int ix = 16 * fx,  iy = 16 * fy;       // IMG*fx//H
        se_out[2 * b]     = cut_start(ix);
        se_out[2 * b + 1] = cut_start(iy);
    }
}

// One thread per output pixel. Replicates reference fp32 math exactly.
__global__ __launch_bounds__(256) void bilinear_kernel(
    const float* __restrict__ x, const int* __restrict__ se, float* __restrict__ out)
{
    const int gid = blockIdx.x * 256 + threadIdx.x;
    const int j  = gid & 255;
    const int i  = (gid >> 8) & 255;
    const int bc = gid >> 16;          // b*3 + c, 0..383
    const int b  = bc / 3;

    const float scale = (float)(229.0 / 255.0);   // (CROP-1)/(IMG-1) in fp32

    float si = (float)i * scale;
    int   i0 = (int)floorf(si);
    float wi = si - (float)i0;
    int   i1 = min(i0 + 1, CROPW - 1);

    float sj = (float)j * scale;
    int   j0 = (int)floorf(sj);
    float wj = sj - (float)j0;
    int   j1 = min(j0 + 1, CROPW - 1);

    const int x0 = se[2 * b];
    const int y0 = se[2 * b + 1];

    const float* img = x + (size_t)bc * (IMG * IMG);
    const int r0 = (x0 + i0) << 8;
    const int r1 = (x0 + i1) << 8;
    const int c0 = y0 + j0;
    const int c1 = y0 + j1;

    float A = img[r0 + c0];
    float Bv = img[r0 + c1];
    float C = img[r1 + c0];
    float D = img[r1 + c1];

    // rows-first blend (matches reference order), then columns
    float l = A  * (1.0f - wi) + C * wi;
    float r = Bv * (1.0f - wi) + D * wi;
    out[gid] = l * (1.0f - wj) + r * wj;
}

extern "C" void kernel_launch(void* const* d_in, const int* in_sizes, int n_in,
                              void* d_out, int out_size, void* d_ws, size_t ws_size,
                              hipStream_t stream) {
    const float* x  = (const float*)d_in[0];   // (128,3,256,256)
    const float* fm = (const float*)d_in[1];   // (128,512,16,16)
    float* out = (float*)d_out;                // (128,3,256,256)
    int* se = (int*)d_ws;                      // 128 * 2 ints

    cam_argmax_kernel<<<128, 256, 0, stream>>>(fm, se);

    const int total = 128 * 3 * 256 * 256;     // 25165824
    bilinear_kernel<<<total / 256, 256, 0, stream>>>(x, se, out);
}

// Round 2
// 74.862 us; speedup vs baseline: 1.8707x; 1.8707x over previous
//
#include <hip/hip_runtime.h>

#define IMG 256
#define CROPW 230
#define REMAIN 115
#define NGROUP 16          // channel groups per batch
#define GCH    32          // channels per group (16*32 = 512)

__device__ __forceinline__ int cut_start(int v) {
    int xy = IMG - v;
    return (v <= REMAIN) ? 0 : ((xy <= REMAIN) ? (IMG - CROPW) : (v - REMAIN));
}

// Grid: 128*16 blocks. Each block: 32 channels of one batch -> partial cam[256].
__global__ __launch_bounds__(256) void cam_partial_kernel(
    const float* __restrict__ fm, float* __restrict__ cam_part)
{
    const int blk = blockIdx.x;
    const int b = blk >> 4;
    const int g = blk & (NGROUP - 1);
    const int tid = threadIdx.x;
    const int lane = tid & 63;
    const int wave = tid >> 6;

    __shared__ float tile[GCH * 256];   // 32 KB
    __shared__ float fw[GCH];

    const float* src = fm + ((size_t)b * 512 + (size_t)g * GCH) * 256;

    // Stage 32 KB into LDS: 2048 float4, 8 per thread, coalesced.
    const float4* src4 = (const float4*)src;
    float4* tile4 = (float4*)tile;
    #pragma unroll
    for (int k = 0; k < 8; ++k)
        tile4[tid + k * 256] = src4[tid + k * 256];
    __syncthreads();

    // fw[c] = mean over the 256 spatial elems. Wave w handles channels w*8..w*8+7.
    for (int c = wave * 8; c < wave * 8 + 8; ++c) {
        const float* row = tile + c * 256;
        float s = row[lane] + row[lane + 64] + row[lane + 128] + row[lane + 192];
        #pragma unroll
        for (int off = 32; off >= 1; off >>= 1)
            s += __shfl_xor(s, off, 64);
        if (lane == 0) fw[c] = s * (1.0f / 256.0f);
    }
    __syncthreads();

    // Partial cam for position p = tid over this block's 32 channels.
    float acc = 0.0f;
    #pragma unroll
    for (int c = 0; c < GCH; ++c) {
        float v = fw[c] * tile[c * 256 + tid];
        acc += (v > 0.0f) ? v : 0.0f;
    }
    cam_part[(size_t)blk * 256 + tid] = acc;   // positive 1/512 scale dropped (argmax-invariant)
}

// Grid: 128 blocks. Sum the 16 partials, argmax (first-occurrence), crop origin.
__global__ __launch_bounds__(256) void argmax_kernel(
    const float* __restrict__ cam_part, int* __restrict__ se_out)
{
    const int b = blockIdx.x;
    const int tid = threadIdx.x;

    __shared__ float s_val[256];
    __shared__ int   s_idx[256];

    float acc = 0.0f;
    #pragma unroll
    for (int g = 0; g < NGROUP; ++g)
        acc += cam_part[((size_t)b * NGROUP + g) * 256 + tid];

    s_val[tid] = acc;
    s_idx[tid] = tid;
    __syncthreads();

    for (int stride = 128; stride >= 1; stride >>= 1) {
        if (tid < stride) {
            float v2 = s_val[tid + stride]; int i2 = s_idx[tid + stride];
            float v1 = s_val[tid];          int i1 = s_idx[tid];
            if (v2 > v1 || (v2 == v1 && i2 < i1)) { s_val[tid] = v2; s_idx[tid] = i2; }
        }
        __syncthreads();
    }

    if (tid == 0) {
        int idx = s_idx[0];
        int fx = idx >> 4, fy = idx & 15;      // H = W = 16
        int ix = 16 * fx,  iy = 16 * fy;       // IMG*fx//H
        se_out[2 * b]     = cut_start(ix);
        se_out[2 * b + 1] = cut_start(iy);
    }
}

// One thread per output pixel. Replicates reference fp32 math exactly.
__global__ __launch_bounds__(256) void bilinear_kernel(
    const float* __restrict__ x, const int* __restrict__ se, float* __restrict__ out)
{
    const int gid = blockIdx.x * 256 + threadIdx.x;
    const int j  = gid & 255;
    const int i  = (gid >> 8) & 255;
    const int bc = gid >> 16;          // b*3 + c, 0..383
    const int b  = bc / 3;

    const float scale = (float)(229.0 / 255.0);   // (CROP-1)/(IMG-1) in fp32

    float si = (float)i * scale;
    int   i0 = (int)floorf(si);
    float wi = si - (float)i0;
    int   i1 = min(i0 + 1, CROPW - 1);

    float sj = (float)j * scale;
    int   j0 = (int)floorf(sj);
    float wj = sj - (float)j0;
    int   j1 = min(j0 + 1, CROPW - 1);

    const int x0 = se[2 * b];
    const int y0 = se[2 * b + 1];

    const float* img = x + (size_t)bc * (IMG * IMG);
    const int r0 = (x0 + i0) << 8;
    const int r1 = (x0 + i1) << 8;
    const int c0 = y0 + j0;
    const int c1 = y0 + j1;

    float A  = img[r0 + c0];
    float Bv = img[r0 + c1];
    float C  = img[r1 + c0];
    float D  = img[r1 + c1];

    // rows-first blend (matches reference order), then columns
    float l = A  * (1.0f - wi) + C * wi;
    float r = Bv * (1.0f - wi) + D * wi;
    out[gid] = l * (1.0f - wj) + r * wj;
}

extern "C" void kernel_launch(void* const* d_in, const int* in_sizes, int n_in,
                              void* d_out, int out_size, void* d_ws, size_t ws_size,
                              hipStream_t stream) {
    const float* x  = (const float*)d_in[0];   // (128,3,256,256)
    const float* fm = (const float*)d_in[1];   // (128,512,16,16)
    float* out = (float*)d_out;                // (128,3,256,256)

    int*   se       = (int*)d_ws;                               // 128*2 ints
    float* cam_part = (float*)((char*)d_ws + 1024);             // 128*16*256 floats = 2 MB

    cam_partial_kernel<<<128 * NGROUP, 256, 0, stream>>>(fm, cam_part);
    argmax_kernel<<<128, 256, 0, stream>>>(cam_part, se);

    const int total = 128 * 3 * 256 * 256;     // 25165824
    bilinear_kernel<<<total / 256, 256, 0, stream>>>(x, se, out);
}

// Round 3
// 56.021 us; speedup vs baseline: 2.4999x; 1.3363x over previous
//
#include <hip/hip_runtime.h>

#define IMG 256
#define CROPW 230
#define REMAIN 115
#define NGROUP 16          // channel groups per batch
#define GCH    32          // channels per group (16*32 = 512)
#define TILE_I 32          // output rows per bilinear block
#define MAXROWS 30         // max input rows needed per tile (ceil(31*scale)+2)

__device__ __forceinline__ int cut_start(int v) {
    int xy = IMG - v;
    return (v <= REMAIN) ? 0 : ((xy <= REMAIN) ? (IMG - CROPW) : (v - REMAIN));
}

// Grid: 128*16 blocks. Each block: 32 channels of one batch -> partial cam[256].
__global__ __launch_bounds__(256) void cam_partial_kernel(
    const float* __restrict__ fm, float* __restrict__ cam_part)
{
    const int blk = blockIdx.x;
    const int b = blk >> 4;
    const int g = blk & (NGROUP - 1);
    const int tid = threadIdx.x;
    const int lane = tid & 63;
    const int wave = tid >> 6;

    __shared__ float tile[GCH * 256];   // 32 KB
    __shared__ float fw[GCH];

    const float* src = fm + ((size_t)b * 512 + (size_t)g * GCH) * 256;

    // Stage 32 KB into LDS: 2048 float4, 8 per thread, coalesced.
    const float4* src4 = (const float4*)src;
    float4* tile4 = (float4*)tile;
    #pragma unroll
    for (int k = 0; k < 8; ++k)
        tile4[tid + k * 256] = src4[tid + k * 256];
    __syncthreads();

    // fw[c] = mean over the 256 spatial elems. Wave w handles channels w*8..w*8+7.
    for (int c = wave * 8; c < wave * 8 + 8; ++c) {
        const float* row = tile + c * 256;
        float s = row[lane] + row[lane + 64] + row[lane + 128] + row[lane + 192];
        #pragma unroll
        for (int off = 32; off >= 1; off >>= 1)
            s += __shfl_xor(s, off, 64);
        if (lane == 0) fw[c] = s * (1.0f / 256.0f);
    }
    __syncthreads();

    // Partial cam for position p = tid over this block's 32 channels.
    float acc = 0.0f;
    #pragma unroll
    for (int c = 0; c < GCH; ++c) {
        float v = fw[c] * tile[c * 256 + tid];
        acc += (v > 0.0f) ? v : 0.0f;
    }
    cam_part[(size_t)blk * 256 + tid] = acc;   // positive 1/512 scale dropped (argmax-invariant)
}

// Grid: 128 blocks. Sum the 16 partials, argmax (first-occurrence), crop origin.
__global__ __launch_bounds__(256) void argmax_kernel(
    const float* __restrict__ cam_part, int* __restrict__ se_out)
{
    const int b = blockIdx.x;
    const int tid = threadIdx.x;

    __shared__ float s_val[256];
    __shared__ int   s_idx[256];

    float acc = 0.0f;
    #pragma unroll
    for (int g = 0; g < NGROUP; ++g)
        acc += cam_part[((size_t)b * NGROUP + g) * 256 + tid];

    s_val[tid] = acc;
    s_idx[tid] = tid;
    __syncthreads();

    for (int stride = 128; stride >= 1; stride >>= 1) {
        if (tid < stride) {
            float v2 = s_val[tid + stride]; int i2 = s_idx[tid + stride];
            float v1 = s_val[tid];          int i1 = s_idx[tid];
            if (v2 > v1 || (v2 == v1 && i2 < i1)) { s_val[tid] = v2; s_idx[tid] = i2; }
        }
        __syncthreads();
    }

    if (tid == 0) {
        int idx = s_idx[0];
        int fx = idx >> 4, fy = idx & 15;      // H = W = 16
        int ix = 16 * fx,  iy = 16 * fy;       // IMG*fx//H
        se_out[2 * b]     = cut_start(ix);
        se_out[2 * b + 1] = cut_start(iy);
    }
}

// Grid: 384 * 8 blocks. Block = one (b,c) image x 32 output rows, staged via LDS.
// Per-pixel fp32 math identical to the reference (verified in round 1/2).
__global__ __launch_bounds__(256) void bilinear_tiled_kernel(
    const float* __restrict__ x, const int* __restrict__ se, float* __restrict__ out)
{
    __shared__ float rows[MAXROWS * 256];   // 30 KB

    const int bx = blockIdx.x;
    const int bc = bx >> 3;                 // image index (b*3 + c)
    const int ib = (bx & 7) * TILE_I;       // first output row of this tile
    const int b  = bc / 3;
    const int tid = threadIdx.x;

    const int x0 = se[2 * b];
    const int y0 = se[2 * b + 1];

    const float scale = (float)(229.0 / 255.0);   // (CROP-1)/(IMG-1) in fp32

    // Input row range needed by output rows [ib, ib+TILE_I)
    const int i0_first = (int)floorf((float)ib * scale);
    const int i0_last  = (int)floorf((float)(ib + TILE_I - 1) * scale);
    const int r_first  = x0 + i0_first;
    const int r_last   = x0 + min(i0_last + 1, CROPW - 1);
    const int nrows    = r_last - r_first + 1;    // <= MAXROWS

    // Stage rows [r_first, r_last] (full 256-wide) into LDS, coalesced float4.
    const float4* src4 = (const float4*)(x + (size_t)bc * (IMG * IMG) + (size_t)r_first * IMG);
    float4* rows4 = (float4*)rows;
    for (int k = tid; k < nrows * (IMG / 4); k += 256)
        rows4[k] = src4[k];
    __syncthreads();

    // Thread = one output column j; hoisted column weights.
    const int j = tid;
    const float sj = (float)j * scale;
    const int   j0 = (int)floorf(sj);
    const float wj = sj - (float)j0;
    const int   j1 = min(j0 + 1, CROPW - 1);
    const int   c0 = y0 + j0;
    const int   c1 = y0 + j1;
    const float owj = 1.0f - wj;

    float* outp = out + (size_t)bc * (IMG * IMG) + (size_t)ib * IMG + j;

    #pragma unroll
    for (int il = 0; il < TILE_I; ++il) {
        const int i = ib + il;
        const float si = (float)i * scale;
        const int   i0 = (int)floorf(si);
        const float wi = si - (float)i0;
        const int   i1 = min(i0 + 1, CROPW - 1);
        const int   row0 = (x0 + i0 - r_first) << 8;
        const int   row1 = (x0 + i1 - r_first) << 8;

        const float A  = rows[row0 + c0];
        const float Bv = rows[row0 + c1];
        const float C  = rows[row1 + c0];
        const float D  = rows[row1 + c1];

        const float l = A  * (1.0f - wi) + C * wi;
        const float r = Bv * (1.0f - wi) + D * wi;
        outp[il * IMG] = l * owj + r * wj;
    }
}

extern "C" void kernel_launch(void* const* d_in, const int* in_sizes, int n_in,
                              void* d_out, int out_size, void* d_ws, size_t ws_size,
                              hipStream_t stream) {
    const float* x  = (const float*)d_in[0];   // (128,3,256,256)
    const float* fm = (const float*)d_in[1];   // (128,512,16,16)
    float* out = (float*)d_out;                // (128,3,256,256)

    int*   se       = (int*)d_ws;                               // 128*2 ints
    float* cam_part = (float*)((char*)d_ws + 1024);             // 128*16*256 floats = 2 MB

    cam_partial_kernel<<<128 * NGROUP, 256, 0, stream>>>(fm, cam_part);
    argmax_kernel<<<128, 256, 0, stream>>>(cam_part, se);

    bilinear_tiled_kernel<<<384 * 8, 256, 0, stream>>>(x, se, out);
}

// Round 4
// 55.562 us; speedup vs baseline: 2.5206x; 1.0083x over previous
//
#include <hip/hip_runtime.h>

#define IMG 256
#define CROPW 230
#define REMAIN 115
#define NGROUP 16          // channel groups per batch
#define GCH    32          // channels per group (16*32 = 512)
#define TILE_I 16          // output rows per bilinear block
#define MAXROWS 16         // max input rows per tile: floor(15*scale)+2 = 16
#define NTILE  16          // tiles per image (256 / TILE_I)

__device__ __forceinline__ int cut_start(int v) {
    int xy = IMG - v;
    return (v <= REMAIN) ? 0 : ((xy <= REMAIN) ? (IMG - CROPW) : (v - REMAIN));
}

// Grid: 128*16 blocks. Each block: 32 channels of one batch -> partial cam[256].
__global__ __launch_bounds__(256) void cam_partial_kernel(
    const float* __restrict__ fm, float* __restrict__ cam_part)
{
    const int blk = blockIdx.x;
    const int b = blk >> 4;
    const int g = blk & (NGROUP - 1);
    const int tid = threadIdx.x;
    const int lane = tid & 63;
    const int wave = tid >> 6;

    __shared__ float tile[GCH * 256];   // 32 KB
    __shared__ float fw[GCH];

    const float* src = fm + ((size_t)b * 512 + (size_t)g * GCH) * 256;

    // Stage 32 KB into LDS: 2048 float4, 8 per thread, coalesced.
    const float4* src4 = (const float4*)src;
    float4* tile4 = (float4*)tile;
    #pragma unroll
    for (int k = 0; k < 8; ++k)
        tile4[tid + k * 256] = src4[tid + k * 256];
    __syncthreads();

    // fw[c] = mean over the 256 spatial elems. Wave w handles channels w*8..w*8+7.
    for (int c = wave * 8; c < wave * 8 + 8; ++c) {
        const float* row = tile + c * 256;
        float s = row[lane] + row[lane + 64] + row[lane + 128] + row[lane + 192];
        #pragma unroll
        for (int off = 32; off >= 1; off >>= 1)
            s += __shfl_xor(s, off, 64);
        if (lane == 0) fw[c] = s * (1.0f / 256.0f);
    }
    __syncthreads();

    // Partial cam for position p = tid over this block's 32 channels.
    float acc = 0.0f;
    #pragma unroll
    for (int c = 0; c < GCH; ++c) {
        float v = fw[c] * tile[c * 256 + tid];
        acc += (v > 0.0f) ? v : 0.0f;
    }
    cam_part[(size_t)blk * 256 + tid] = acc;   // positive 1/512 scale dropped (argmax-invariant)
}

// Grid: 128 blocks. Sum the 16 partials, argmax (first-occurrence), crop origin.
__global__ __launch_bounds__(256) void argmax_kernel(
    const float* __restrict__ cam_part, int* __restrict__ se_out)
{
    const int b = blockIdx.x;
    const int tid = threadIdx.x;

    __shared__ float s_val[256];
    __shared__ int   s_idx[256];

    float acc = 0.0f;
    #pragma unroll
    for (int g = 0; g < NGROUP; ++g)
        acc += cam_part[((size_t)b * NGROUP + g) * 256 + tid];

    s_val[tid] = acc;
    s_idx[tid] = tid;
    __syncthreads();

    for (int stride = 128; stride >= 1; stride >>= 1) {
        if (tid < stride) {
            float v2 = s_val[tid + stride]; int i2 = s_idx[tid + stride];
            float v1 = s_val[tid];          int i1 = s_idx[tid];
            if (v2 > v1 || (v2 == v1 && i2 < i1)) { s_val[tid] = v2; s_idx[tid] = i2; }
        }
        __syncthreads();
    }

    if (tid == 0) {
        int idx = s_idx[0];
        int fx = idx >> 4, fy = idx & 15;      // H = W = 16
        int ix = 16 * fx,  iy = 16 * fy;       // IMG*fx//H
        se_out[2 * b]     = cut_start(ix);
        se_out[2 * b + 1] = cut_start(iy);
    }
}

// Grid: 384 * 16 blocks. Block = one (b,c) image x 16 output rows via 16 KB LDS.
// 16 KB LDS -> 8 blocks/CU (full 32-wave occupancy).
// Per-pixel fp32 math identical to the reference (verified rounds 1-3).
__global__ __launch_bounds__(256) void bilinear_tiled_kernel(
    const float* __restrict__ x, const int* __restrict__ se, float* __restrict__ out)
{
    __shared__ float rows[MAXROWS * 256];   // 16 KB

    const int bx = blockIdx.x;
    const int bc = bx >> 4;                 // image index (b*3 + c)
    const int ib = (bx & 15) * TILE_I;      // first output row of this tile
    const int b  = bc / 3;
    const int tid = threadIdx.x;

    const int x0 = se[2 * b];
    const int y0 = se[2 * b + 1];

    const float scale = (float)(229.0 / 255.0);   // (CROP-1)/(IMG-1) in fp32

    // Input row range needed by output rows [ib, ib+TILE_I)
    const int i0_first = (int)floorf((float)ib * scale);
    const int i0_last  = (int)floorf((float)(ib + TILE_I - 1) * scale);
    const int r_first  = x0 + i0_first;
    const int r_last   = x0 + min(i0_last + 1, CROPW - 1);
    const int nrows    = r_last - r_first + 1;    // <= MAXROWS

    // Stage rows [r_first, r_last] (full 256-wide) into LDS, coalesced float4.
    const float4* src4 = (const float4*)(x + (size_t)bc * (IMG * IMG) + (size_t)r_first * IMG);
    float4* rows4 = (float4*)rows;
    for (int k = tid; k < nrows * (IMG / 4); k += 256)
        rows4[k] = src4[k];
    __syncthreads();

    // Thread = one output column j; hoisted column weights.
    const int j = tid;
    const float sj = (float)j * scale;
    const int   j0 = (int)floorf(sj);
    const float wj = sj - (float)j0;
    const int   j1 = min(j0 + 1, CROPW - 1);
    const int   c0 = y0 + j0;
    const int   c1 = y0 + j1;
    const float owj = 1.0f - wj;

    float* outp = out + (size_t)bc * (IMG * IMG) + (size_t)ib * IMG + j;

    #pragma unroll
    for (int il = 0; il < TILE_I; ++il) {
        const int i = ib + il;
        const float si = (float)i * scale;
        const int   i0 = (int)floorf(si);
        const float wi = si - (float)i0;
        const int   i1 = min(i0 + 1, CROPW - 1);
        const int   row0 = (x0 + i0 - r_first) << 8;
        const int   row1 = (x0 + i1 - r_first) << 8;

        const float A  = rows[row0 + c0];
        const float Bv = rows[row0 + c1];
        const float C  = rows[row1 + c0];
        const float D  = rows[row1 + c1];

        const float l = A  * (1.0f - wi) + C * wi;
        const float r = Bv * (1.0f - wi) + D * wi;
        outp[il * IMG] = l * owj + r * wj;
    }
}

extern "C" void kernel_launch(void* const* d_in, const int* in_sizes, int n_in,
                              void* d_out, int out_size, void* d_ws, size_t ws_size,
                              hipStream_t stream) {
    const float* x  = (const float*)d_in[0];   // (128,3,256,256)
    const float* fm = (const float*)d_in[1];   // (128,512,16,16)
    float* out = (float*)d_out;                // (128,3,256,256)

    int*   se       = (int*)d_ws;                               // 128*2 ints
    float* cam_part = (float*)((char*)d_ws + 1024);             // 128*16*256 floats = 2 MB

    cam_partial_kernel<<<128 * NGROUP, 256, 0, stream>>>(fm, cam_part);
    argmax_kernel<<<128, 256, 0, stream>>>(cam_part, se);

    bilinear_tiled_kernel<<<384 * NTILE, 256, 0, stream>>>(x, se, out);
}